// Round 1
// baseline (159.641 us; speedup 1.0000x reference)
//
#include <hip/hip_runtime.h>

// WassersteinLoss: out = scale * sum_{b,c,t} |a-b| * (T - t)
// scale = 2 / (T*C*(T+1)*B). Memory-bound single-pass reduction.

#define T_DIM 8192
#define T_MASK 8191

__global__ __launch_bounds__(256)
void WassersteinLoss_kernel(const float4* __restrict__ a,
                            const float4* __restrict__ b,
                            float* __restrict__ out,
                            int n4, float scale) {
    int tid = blockIdx.x * blockDim.x + threadIdx.x;
    int stride = gridDim.x * blockDim.x;

    float acc = 0.0f;
    for (int v = tid; v < n4; v += stride) {
        float4 x = a[v];
        float4 y = b[v];
        // element index of .x is 4*v; t = (4*v) & (T-1). 4 | T so all 4
        // elements share the same row (no wrap within the float4).
        int t = (v << 2) & T_MASK;
        float w = (float)(T_DIM - t);
        float d0 = fabsf(x.x - y.x);
        float d1 = fabsf(x.y - y.y);
        float d2 = fabsf(x.z - y.z);
        float d3 = fabsf(x.w - y.w);
        // w*d0 + (w-1)*d1 + (w-2)*d2 + (w-3)*d3
        acc += w * (d0 + d1 + d2 + d3) - (d1 + 2.0f * d2 + 3.0f * d3);
    }

    // wave-64 shuffle reduction
    #pragma unroll
    for (int off = 32; off > 0; off >>= 1)
        acc += __shfl_down(acc, off, 64);

    __shared__ float wave_sums[4];  // 256 threads / 64 lanes = 4 waves
    int lane = threadIdx.x & 63;
    int wave = threadIdx.x >> 6;
    if (lane == 0) wave_sums[wave] = acc;
    __syncthreads();

    if (threadIdx.x == 0) {
        float s = wave_sums[0] + wave_sums[1] + wave_sums[2] + wave_sums[3];
        atomicAdd(out, s * scale);  // device-scope by default on CDNA
    }
}

extern "C" void kernel_launch(void* const* d_in, const int* in_sizes, int n_in,
                              void* d_out, int out_size, void* d_ws, size_t ws_size,
                              hipStream_t stream) {
    const float* a = (const float*)d_in[0];
    const float* b = (const float*)d_in[1];
    float* out = (float*)d_out;

    int n = in_sizes[0];            // B*C*T = 16,777,216
    int n4 = n >> 2;                // float4 count

    const long long T = T_DIM;
    const long long C = 64;
    const long long B = (long long)n / (C * T);
    float scale = (float)(2.0 / ((double)T * (double)C * (double)(T + 1) * (double)B));

    // d_out is poisoned to 0xAA before every launch — zero it on-stream.
    hipMemsetAsync(out, 0, sizeof(float) * out_size, stream);

    const int threads = 256;
    const int blocks = 2048;        // 8 waves/CU-equivalent oversubscription; 8 vec4 iters/thread
    WassersteinLoss_kernel<<<blocks, threads, 0, stream>>>(
        (const float4*)a, (const float4*)b, out, n4, scale);
}

// Round 2
// 146.074 us; speedup vs baseline: 1.0929x; 1.0929x over previous
//
#include <hip/hip_runtime.h>

// WassersteinLoss: out = scale * sum_{b,c,t} |a-b| * (T - t)
// scale = 2 / (T*C*(T+1)*B). Memory-bound; optimize for MLP (batch-8 loads
// in flight) + two-stage reduction (no atomics, no memset).

#define T_DIM 8192
#define T_MASK 8191
#define BATCH 8

__global__ __launch_bounds__(256)
void wl_partial_kernel(const float4* __restrict__ a,
                       const float4* __restrict__ b,
                       float* __restrict__ partial,
                       int n4) {
    int tid = blockIdx.x * blockDim.x + threadIdx.x;
    int stride = gridDim.x * blockDim.x;

    float acc = 0.0f;
    int v = tid;

    // Main path: batch of 8 strided float4-pairs; all 16 loads issued before
    // any consumption so the wave has 16 outstanding VMEM ops (latency hiding).
    for (; v + (BATCH - 1) * stride < n4; v += BATCH * stride) {
        float4 xa[BATCH], xb[BATCH];
        #pragma unroll
        for (int i = 0; i < BATCH; ++i) xa[i] = a[v + i * stride];
        #pragma unroll
        for (int i = 0; i < BATCH; ++i) xb[i] = b[v + i * stride];
        #pragma unroll
        for (int i = 0; i < BATCH; ++i) {
            int idx = v + i * stride;
            // element index of .x is 4*idx; 4 | T so no row wrap inside float4
            float w = (float)(T_DIM - ((idx << 2) & T_MASK));
            float d0 = fabsf(xa[i].x - xb[i].x);
            float d1 = fabsf(xa[i].y - xb[i].y);
            float d2 = fabsf(xa[i].z - xb[i].z);
            float d3 = fabsf(xa[i].w - xb[i].w);
            acc += w * (d0 + d1 + d2 + d3) - (d1 + 2.0f * d2 + 3.0f * d3);
        }
    }
    // Tail (empty for the shipped shape: n4 = 4M divides exactly)
    for (; v < n4; v += stride) {
        float4 x = a[v];
        float4 y = b[v];
        float w = (float)(T_DIM - ((v << 2) & T_MASK));
        float d0 = fabsf(x.x - y.x);
        float d1 = fabsf(x.y - y.y);
        float d2 = fabsf(x.z - y.z);
        float d3 = fabsf(x.w - y.w);
        acc += w * (d0 + d1 + d2 + d3) - (d1 + 2.0f * d2 + 3.0f * d3);
    }

    // wave-64 shuffle reduction
    #pragma unroll
    for (int off = 32; off > 0; off >>= 1)
        acc += __shfl_down(acc, off, 64);

    __shared__ float wave_sums[4];
    int lane = threadIdx.x & 63;
    int wave = threadIdx.x >> 6;
    if (lane == 0) wave_sums[wave] = acc;
    __syncthreads();

    if (threadIdx.x == 0)
        partial[blockIdx.x] = wave_sums[0] + wave_sums[1] + wave_sums[2] + wave_sums[3];
}

__global__ __launch_bounds__(256)
void wl_final_kernel(const float* __restrict__ partial, int n,
                     float* __restrict__ out, float scale) {
    float acc = 0.0f;
    for (int i = threadIdx.x; i < n; i += 256)
        acc += partial[i];

    #pragma unroll
    for (int off = 32; off > 0; off >>= 1)
        acc += __shfl_down(acc, off, 64);

    __shared__ float wave_sums[4];
    int lane = threadIdx.x & 63;
    int wave = threadIdx.x >> 6;
    if (lane == 0) wave_sums[wave] = acc;
    __syncthreads();

    if (threadIdx.x == 0)
        out[0] = (wave_sums[0] + wave_sums[1] + wave_sums[2] + wave_sums[3]) * scale;
}

extern "C" void kernel_launch(void* const* d_in, const int* in_sizes, int n_in,
                              void* d_out, int out_size, void* d_ws, size_t ws_size,
                              hipStream_t stream) {
    const float* a = (const float*)d_in[0];
    const float* b = (const float*)d_in[1];
    float* out = (float*)d_out;
    float* partial = (float*)d_ws;   // 2048 floats = 8 KB scratch

    int n = in_sizes[0];             // B*C*T = 16,777,216
    int n4 = n >> 2;

    const long long T = T_DIM;
    const long long C = 64;
    const long long B = (long long)n / (C * T);
    float scale = (float)(2.0 / ((double)T * (double)C * (double)(T + 1) * (double)B));

    const int threads = 256;
    const int blocks = 2048;         // 8 blocks/CU; exactly 1 batch-8 iter/thread
    wl_partial_kernel<<<blocks, threads, 0, stream>>>(
        (const float4*)a, (const float4*)b, partial, n4);
    wl_final_kernel<<<1, threads, 0, stream>>>(partial, blocks, out, scale);
}

// Round 3
// 143.323 us; speedup vs baseline: 1.1139x; 1.0192x over previous
//
#include <hip/hip_runtime.h>

// WassersteinLoss: out = scale * sum_{b,c,t} |a-b| * (T - t)
// scale = 2 / (T*C*(T+1)*B).
// R2: nontemporal (nt) loads to bypass L1 allocation (theory: L1 MSHR cap
// ~5 B/cyc/CU is the limiter, proven by L3-resident dispatch at same dur),
// batch-4 / 4096 blocks for full occupancy, independent accumulators.

#define T_DIM 8192
#define T_MASK 8191
#define BATCH 4

typedef float vfloat4 __attribute__((ext_vector_type(4)));

__global__ __launch_bounds__(256)
void wl_partial_kernel(const vfloat4* __restrict__ a,
                       const vfloat4* __restrict__ b,
                       float* __restrict__ partial,
                       int n4) {
    int tid = blockIdx.x * blockDim.x + threadIdx.x;
    int stride = gridDim.x * blockDim.x;

    float acc0 = 0.0f, acc1 = 0.0f, acc2 = 0.0f, acc3 = 0.0f;
    int v = tid;

    for (; v + (BATCH - 1) * stride < n4; v += BATCH * stride) {
        vfloat4 xa[BATCH], xb[BATCH];
        #pragma unroll
        for (int i = 0; i < BATCH; ++i) {
            xa[i] = __builtin_nontemporal_load(&a[v + i * stride]);
            xb[i] = __builtin_nontemporal_load(&b[v + i * stride]);
        }
        #pragma unroll
        for (int i = 0; i < BATCH; ++i) {
            int idx = v + i * stride;
            float w = (float)(T_DIM - ((idx << 2) & T_MASK));
            float d0 = fabsf(xa[i].x - xb[i].x);
            float d1 = fabsf(xa[i].y - xb[i].y);
            float d2 = fabsf(xa[i].z - xb[i].z);
            float d3 = fabsf(xa[i].w - xb[i].w);
            float s = w * (d0 + d1 + d2 + d3) - (d1 + 2.0f * d2 + 3.0f * d3);
            // 4 independent accumulator chains
            if (i == 0) acc0 += s;
            else if (i == 1) acc1 += s;
            else if (i == 2) acc2 += s;
            else acc3 += s;
        }
    }
    // Tail (empty for the shipped shape)
    for (; v < n4; v += stride) {
        vfloat4 x = __builtin_nontemporal_load(&a[v]);
        vfloat4 y = __builtin_nontemporal_load(&b[v]);
        float w = (float)(T_DIM - ((v << 2) & T_MASK));
        float d0 = fabsf(x.x - y.x);
        float d1 = fabsf(x.y - y.y);
        float d2 = fabsf(x.z - y.z);
        float d3 = fabsf(x.w - y.w);
        acc0 += w * (d0 + d1 + d2 + d3) - (d1 + 2.0f * d2 + 3.0f * d3);
    }

    float acc = (acc0 + acc1) + (acc2 + acc3);

    #pragma unroll
    for (int off = 32; off > 0; off >>= 1)
        acc += __shfl_down(acc, off, 64);

    __shared__ float wave_sums[4];
    int lane = threadIdx.x & 63;
    int wave = threadIdx.x >> 6;
    if (lane == 0) wave_sums[wave] = acc;
    __syncthreads();

    if (threadIdx.x == 0)
        partial[blockIdx.x] = wave_sums[0] + wave_sums[1] + wave_sums[2] + wave_sums[3];
}

__global__ __launch_bounds__(256)
void wl_final_kernel(const float* __restrict__ partial, int n,
                     float* __restrict__ out, float scale) {
    float acc = 0.0f;
    for (int i = threadIdx.x; i < n; i += 256)
        acc += partial[i];

    #pragma unroll
    for (int off = 32; off > 0; off >>= 1)
        acc += __shfl_down(acc, off, 64);

    __shared__ float wave_sums[4];
    int lane = threadIdx.x & 63;
    int wave = threadIdx.x >> 6;
    if (lane == 0) wave_sums[wave] = acc;
    __syncthreads();

    if (threadIdx.x == 0)
        out[0] = (wave_sums[0] + wave_sums[1] + wave_sums[2] + wave_sums[3]) * scale;
}

extern "C" void kernel_launch(void* const* d_in, const int* in_sizes, int n_in,
                              void* d_out, int out_size, void* d_ws, size_t ws_size,
                              hipStream_t stream) {
    const float* a = (const float*)d_in[0];
    const float* b = (const float*)d_in[1];
    float* out = (float*)d_out;
    float* partial = (float*)d_ws;   // 4096 floats = 16 KB scratch

    int n = in_sizes[0];             // B*C*T = 16,777,216
    int n4 = n >> 2;

    const long long T = T_DIM;
    const long long C = 64;
    const long long B = (long long)n / (C * T);
    float scale = (float)(2.0 / ((double)T * (double)C * (double)(T + 1) * (double)B));

    const int threads = 256;
    const int blocks = 4096;         // n4 / (256*BATCH) — exactly 1 batch iter/thread
    wl_partial_kernel<<<blocks, threads, 0, stream>>>(
        (const vfloat4*)a, (const vfloat4*)b, partial, n4);
    wl_final_kernel<<<1, threads, 0, stream>>>(partial, blocks, out, scale);
}